// Round 1
// 675.028 us; speedup vs baseline: 1.6040x; 1.6040x over previous
//
#include <hip/hip_runtime.h>
#include <hip/hip_cooperative_groups.h>
#include <math.h>

namespace cg = cooperative_groups;

#define EMBED  1024
#define HIDDEN 1024
#define VOCAB  32000
#define TSTEPS 64
#define G4     4096   // 4*HIDDEN
#define NBLK   256    // lstm blocks (1 per CU, cooperative-resident)

// ---------------------------------------------------------------------------
// Kernel 1: build xs[t] = (t==0 ? features : embed_table[captions[t-1]])
// ---------------------------------------------------------------------------
__global__ void build_xs(const int* __restrict__ caps,
                         const float* __restrict__ feat,
                         const float* __restrict__ table,
                         float* __restrict__ xs) {
    int t = blockIdx.x;
    int e = threadIdx.x + blockIdx.y * 256;
    float v;
    if (t == 0) {
        v = feat[e];
    } else {
        size_t row = (size_t)caps[t - 1];
        v = table[row * EMBED + e];
    }
    xs[(size_t)t * EMBED + e] = v;
}

// ---------------------------------------------------------------------------
// Kernel 2: Xg[t][j] = dot(xs[t], W_ih[j]) + b_ih[j] + b_hh[j]
// ---------------------------------------------------------------------------
__global__ __launch_bounds__(256) void xg_gemm(const float* __restrict__ xs,
                                               const float* __restrict__ Wih,
                                               const float* __restrict__ bih,
                                               const float* __restrict__ bhh,
                                               float* __restrict__ Xg) {
    __shared__ float xs_s[64][132];
    int tid = threadIdx.x;
    int jl  = tid & 15;
    int tg  = tid >> 4;
    int j   = blockIdx.x * 16 + jl;
    const float* wrow = Wih + (size_t)j * EMBED;
    float acc[4] = {0.f, 0.f, 0.f, 0.f};

    for (int c = 0; c < 8; ++c) {
        __syncthreads();
        for (int idx = tid; idx < 64 * 32; idx += 256) {
            int r = idx >> 5, f4 = idx & 31;
            float4 v = ((const float4*)(xs + (size_t)r * EMBED + c * 128))[f4];
            *((float4*)&xs_s[r][f4 * 4]) = v;
        }
        __syncthreads();
        for (int f4 = 0; f4 < 32; ++f4) {
            float4 w = ((const float4*)(wrow + c * 128))[f4];
#pragma unroll
            for (int k = 0; k < 4; ++k) {
                const float* xr = &xs_s[tg * 4 + k][f4 * 4];
                acc[k] += w.x * xr[0] + w.y * xr[1] + w.z * xr[2] + w.w * xr[3];
            }
        }
    }
    float bias = bih[j] + bhh[j];
#pragma unroll
    for (int k = 0; k < 4; ++k) {
        Xg[(size_t)(tg * 4 + k) * G4 + j] = acc[k] + bias;
    }
}

// ---------------------------------------------------------------------------
// Kernel 3: sequential LSTM, 256 blocks x 256 threads.
//
// NO grid barrier at all: the h exchange is data-flow-synchronized. Each
// producer lane packs (tag = t+1, h-bits) into ONE 8-byte word and issues a
// single relaxed agent-scope 64-bit atomic store to the LLC. Consumers poll
// the packed words directly (each thread polls exactly the 4 elements it
// stages into LDS). Critical path per step = one LLC store->load-visible
// latency instead of {store, counter-RMW x256 serialized, spin, load}.
//
// Safety: h double-buffered by t&1. A block can only write tag t+2 into
// buffer (t&1) after observing ALL tags t+1, which requires every block
// (including stragglers reading buffer t&1) to have finished its step-t
// read phase -> max skew 1 step, 2 buffers suffice. Tags are monotonic;
// memset-0 gives the correct tag==0 / h==0 initial state.
//
// Wave layout: wave wv (0..3) owns output element hj = 4*blockIdx.x + wv and
// all 4 of its gates; 16-lane group g = lane>>4 computes gate g. Gate
// partials combine with in-wave __shfl (no LDS round-trip), so the loop has
// exactly one __syncthreads per step (h_s LDS double-buffered, Xg in LDS).
// ---------------------------------------------------------------------------
__global__ __launch_bounds__(256, 1) void lstm_seq(const float* __restrict__ Xg,
                                                   const float* __restrict__ Whh,
                                                   unsigned long long* hbuf,  // 2*1024 packed
                                                   float* __restrict__ hs) {
    __shared__ float h_s[2][HIDDEN];
    __shared__ float xg_s[TSTEPS][16];

    int tid  = threadIdx.x;
    int lane = tid & 63;
    int wv   = tid >> 6;          // output sub-index 0..3 (one per wave)
    int g    = lane >> 4;         // gate index 0..3 (i,f,g,o)
    int c16  = lane & 15;
    int q0   = blockIdx.x * 4;
    int hj   = q0 + wv;
    const float4* wrow = (const float4*)(Whh + ((size_t)g * HIDDEN + hj) * HIDDEN);

    // Cache this lane's 64-float W_hh slice in registers (read once from HBM).
    float4 wreg[16];
#pragma unroll
    for (int k = 0; k < 16; ++k) wreg[k] = wrow[c16 + 16 * k];

    // Stage this block's Xg slice: 4 outputs x 4 gates x 64 steps = 4 KB LDS.
    for (int idx = tid; idx < TSTEPS * 16; idx += 256) {
        int t = idx >> 4, r = idx & 15, gg = r >> 2, w = r & 3;
        xg_s[t][r] = Xg[(size_t)t * G4 + gg * HIDDEN + q0 + w];
    }

    float cstate = 0.0f;          // live in lane 0 of each wave only

    for (int t = 0; t < TSTEPS; ++t) {
        // ---- data-flow staged load of h[t-1]: poll packed (tag,value) words
        unsigned long long* hsrc = hbuf + (size_t)(t & 1) * HIDDEN;
        unsigned tag = (unsigned)t;
        float* dst = h_s[t & 1];

        unsigned long long x0 = 0, x1 = 0, x2 = 0, x3 = 0;
        int need = 0xF;
        do {
            if (need & 1) {
                x0 = __hip_atomic_load(hsrc + tid, __ATOMIC_RELAXED,
                                       __HIP_MEMORY_SCOPE_AGENT);
                if ((unsigned)(x0 >> 32) == tag) need &= ~1;
            }
            if (need & 2) {
                x1 = __hip_atomic_load(hsrc + tid + 256, __ATOMIC_RELAXED,
                                       __HIP_MEMORY_SCOPE_AGENT);
                if ((unsigned)(x1 >> 32) == tag) need &= ~2;
            }
            if (need & 4) {
                x2 = __hip_atomic_load(hsrc + tid + 512, __ATOMIC_RELAXED,
                                       __HIP_MEMORY_SCOPE_AGENT);
                if ((unsigned)(x2 >> 32) == tag) need &= ~4;
            }
            if (need & 8) {
                x3 = __hip_atomic_load(hsrc + tid + 768, __ATOMIC_RELAXED,
                                       __HIP_MEMORY_SCOPE_AGENT);
                if ((unsigned)(x3 >> 32) == tag) need &= ~8;
            }
            if (need) __builtin_amdgcn_s_sleep(1);
        } while (need);
        dst[tid]       = __uint_as_float((unsigned)x0);
        dst[tid + 256] = __uint_as_float((unsigned)x1);
        dst[tid + 512] = __uint_as_float((unsigned)x2);
        dst[tid + 768] = __uint_as_float((unsigned)x3);
        __syncthreads();

        // ---- gemv: each 16-lane group computes one gate for this wave's hj
        float4 a = {0.f, 0.f, 0.f, 0.f};
#pragma unroll
        for (int k = 0; k < 16; ++k) {
            float4 w = wreg[k];
            const float* hv = &dst[(c16 + 16 * k) * 4];
            a.x += w.x * hv[0];
            a.y += w.y * hv[1];
            a.z += w.z * hv[2];
            a.w += w.w * hv[3];
        }
        float sum = (a.x + a.y) + (a.z + a.w);
        sum += __shfl_xor(sum, 1);
        sum += __shfl_xor(sum, 2);
        sum += __shfl_xor(sum, 4);
        sum += __shfl_xor(sum, 8);
        // gate partials live in lanes 0,16,32,48 of this wave -> in-wave shfl
        float s0 = __shfl(sum, 0);
        float s1 = __shfl(sum, 16);
        float s2 = __shfl(sum, 32);
        float s3 = __shfl(sum, 48);

        if (lane == 0) {
            float gi = s0 + xg_s[t][wv];
            float gf = s1 + xg_s[t][4 + wv];
            float gg = s2 + xg_s[t][8 + wv];
            float go = s3 + xg_s[t][12 + wv];
            float i_ = 1.f / (1.f + expf(-gi));
            float f_ = 1.f / (1.f + expf(-gf));
            float g_ = tanhf(gg);
            float o_ = 1.f / (1.f + expf(-go));
            cstate = f_ * cstate + i_ * g_;
            float hv = o_ * tanhf(cstate);
            unsigned long long pk =
                ((unsigned long long)(unsigned)(t + 1) << 32) |
                (unsigned long long)__float_as_uint(hv);
            __hip_atomic_store(hbuf + (size_t)((t + 1) & 1) * HIDDEN + hj, pk,
                               __ATOMIC_RELAXED, __HIP_MEMORY_SCOPE_AGENT);
            hs[(size_t)t * HIDDEN + hj] = hv;
        }
        // no trailing barrier: h_s double-buffered, xg_s read-only
    }
}

// ---------------------------------------------------------------------------
// Kernel 4: logits = hs @ fc_W.T + fc_b   [64,1024] x [1024,32000]
// ---------------------------------------------------------------------------
__global__ __launch_bounds__(256) void logits_gemm(const float* __restrict__ hs,
                                                   const float* __restrict__ fcW,
                                                   const float* __restrict__ fcb,
                                                   float* __restrict__ out) {
    __shared__ float hs_s[64][132];
    int tid = threadIdx.x;
    int vl  = tid & 31;
    int tg  = tid >> 5;
    int v   = blockIdx.x * 32 + vl;
    const float* wrow = fcW + (size_t)v * HIDDEN;
    float acc[8] = {0.f, 0.f, 0.f, 0.f, 0.f, 0.f, 0.f, 0.f};

    for (int c = 0; c < 8; ++c) {
        __syncthreads();
        for (int idx = tid; idx < 64 * 32; idx += 256) {
            int r = idx >> 5, f4 = idx & 31;
            float4 h4 = ((const float4*)(hs + (size_t)r * HIDDEN + c * 128))[f4];
            *((float4*)&hs_s[r][f4 * 4]) = h4;
        }
        __syncthreads();
        for (int f4 = 0; f4 < 32; ++f4) {
            float4 w = ((const float4*)(wrow + c * 128))[f4];
#pragma unroll
            for (int k = 0; k < 8; ++k) {
                const float* hv = &hs_s[tg * 8 + k][f4 * 4];
                acc[k] += w.x * hv[0] + w.y * hv[1] + w.z * hv[2] + w.w * hv[3];
            }
        }
    }
    float b = fcb[v];
#pragma unroll
    for (int k = 0; k < 8; ++k) {
        out[(size_t)(tg * 8 + k) * VOCAB + v] = acc[k] + b;
    }
}

// ---------------------------------------------------------------------------
extern "C" void kernel_launch(void* const* d_in, const int* in_sizes, int n_in,
                              void* d_out, int out_size, void* d_ws, size_t ws_size,
                              hipStream_t stream) {
    const int*   caps  = (const int*)  d_in[0];
    const float* feat  = (const float*)d_in[1];
    const float* table = (const float*)d_in[2];
    const float* Wih   = (const float*)d_in[3];
    const float* Whh   = (const float*)d_in[4];
    const float* bih   = (const float*)d_in[5];
    const float* bhh   = (const float*)d_in[6];
    const float* fcW   = (const float*)d_in[7];
    const float* fcb   = (const float*)d_in[8];
    float* out = (float*)d_out;

    char* ws = (char*)d_ws;
    float* xs = (float*)(ws);                                   // 256 KB
    float* Xg = (float*)(ws + 262144);                          // 1 MB
    float* hs = (float*)(ws + 262144 + 1048576);                // 256 KB
    unsigned long long* hbuf =
        (unsigned long long*)(ws + 262144 + 1048576 + 262144);  // 16 KB packed

    // ws is poisoned 0xAA before every timed call: zero the packed h
    // double-buffer (tag==0 <=> valid h==0 initial state).
    hipMemsetAsync(hbuf, 0, 2 * HIDDEN * sizeof(unsigned long long), stream);

    build_xs<<<dim3(TSTEPS, 4), 256, 0, stream>>>(caps, feat, table, xs);
    xg_gemm <<<256, 256, 0, stream>>>(xs, Wih, bih, bhh, Xg);

    void* args[] = {(void*)&Xg, (void*)&Whh, (void*)&hbuf, (void*)&hs};
    hipLaunchCooperativeKernel(lstm_seq, dim3(NBLK), dim3(256), args, 0u, stream);

    logits_gemm<<<VOCAB / 32, 256, 0, stream>>>(hs, fcW, fcb, out);
}

// Round 3
// 650.891 us; speedup vs baseline: 1.6635x; 1.0371x over previous
//
#include <hip/hip_runtime.h>
#include <hip/hip_cooperative_groups.h>
#include <math.h>

namespace cg = cooperative_groups;

#define EMBED  1024
#define HIDDEN 1024
#define VOCAB  32000
#define TSTEPS 64
#define G4     4096   // 4*HIDDEN
#define NBLK   256    // lstm blocks (1 per CU, cooperative-resident)
#define RS     133    // LDS row stride (floats): stride-4-row b128 reads -> 8
                      // disjoint bank-quads, 2-way aliasing = free

// ---------------------------------------------------------------------------
// Kernel 1: build xs[t] = (t==0 ? features : embed_table[captions[t-1]])
// ---------------------------------------------------------------------------
__global__ void build_xs(const int* __restrict__ caps,
                         const float* __restrict__ feat,
                         const float* __restrict__ table,
                         float* __restrict__ xs) {
    int t = blockIdx.x;
    int e = threadIdx.x + blockIdx.y * 256;
    float v;
    if (t == 0) {
        v = feat[e];
    } else {
        size_t row = (size_t)caps[t - 1];
        v = table[row * EMBED + e];
    }
    xs[(size_t)t * EMBED + e] = v;
}

// ---------------------------------------------------------------------------
// Kernel 2: Xg[t][j] = dot(xs[t], W_ih[j]) + b_ih[j] + b_hh[j]
// v2: W_ih staged through LDS with wave-contiguous loads (old version had
// each lane walk its own row at stride 4096B -> HBM channel camping).
// ---------------------------------------------------------------------------
__global__ __launch_bounds__(256) void xg_gemm(const float* __restrict__ xs,
                                               const float* __restrict__ Wih,
                                               const float* __restrict__ bih,
                                               const float* __restrict__ bhh,
                                               float* __restrict__ Xg) {
    __shared__ float xs_s[64][RS];
    __shared__ float w_s[16][RS];
    int tid = threadIdx.x;
    int jl  = tid & 15;           // gate-col within tile
    int tg  = tid >> 4;           // 16 groups x 4 timesteps
    int j0  = blockIdx.x * 16;
    int j   = j0 + jl;
    float acc[4] = {0.f, 0.f, 0.f, 0.f};

    for (int c = 0; c < 8; ++c) {
        __syncthreads();
        // stage xs chunk [64][128] — coalesced
        for (int idx = tid; idx < 64 * 32; idx += 256) {
            int r = idx >> 5, f4 = idx & 31;
            float4 v = ((const float4*)(xs + (size_t)r * EMBED + c * 128))[f4];
            *((float4*)&xs_s[r][f4 * 4]) = v;
        }
        // stage W_ih chunk [16][128] — consecutive lanes read consecutive 16B
        for (int idx = tid; idx < 16 * 32; idx += 256) {
            int r = idx >> 5, f4 = idx & 31;
            float4 v = ((const float4*)(Wih + (size_t)(j0 + r) * EMBED + c * 128))[f4];
            *((float4*)&w_s[r][f4 * 4]) = v;
        }
        __syncthreads();
        for (int f4 = 0; f4 < 32; ++f4) {
            float4 w = *((const float4*)&w_s[jl][f4 * 4]);
#pragma unroll
            for (int k = 0; k < 4; ++k) {
                const float* xr = &xs_s[tg * 4 + k][f4 * 4];
                acc[k] += w.x * xr[0] + w.y * xr[1] + w.z * xr[2] + w.w * xr[3];
            }
        }
    }
    float bias = bih[j] + bhh[j];
#pragma unroll
    for (int k = 0; k < 4; ++k) {
        Xg[(size_t)(tg * 4 + k) * G4 + j] = acc[k] + bias;
    }
}

// ---------------------------------------------------------------------------
// Kernel 3: sequential LSTM, 256 blocks x 256 threads. (unchanged from R1)
//
// NO grid barrier: h exchange is data-flow-synchronized via packed
// (tag, value) 8-byte agent-scope atomics, double-buffered by t&1.
// ---------------------------------------------------------------------------
__global__ __launch_bounds__(256, 1) void lstm_seq(const float* __restrict__ Xg,
                                                   const float* __restrict__ Whh,
                                                   unsigned long long* hbuf,  // 2*1024 packed
                                                   float* __restrict__ hs) {
    __shared__ float h_s[2][HIDDEN];
    __shared__ float xg_s[TSTEPS][16];

    int tid  = threadIdx.x;
    int lane = tid & 63;
    int wv   = tid >> 6;          // output sub-index 0..3 (one per wave)
    int g    = lane >> 4;         // gate index 0..3 (i,f,g,o)
    int c16  = lane & 15;
    int q0   = blockIdx.x * 4;
    int hj   = q0 + wv;
    const float4* wrow = (const float4*)(Whh + ((size_t)g * HIDDEN + hj) * HIDDEN);

    float4 wreg[16];
#pragma unroll
    for (int k = 0; k < 16; ++k) wreg[k] = wrow[c16 + 16 * k];

    for (int idx = tid; idx < TSTEPS * 16; idx += 256) {
        int t = idx >> 4, r = idx & 15, gg = r >> 2, w = r & 3;
        xg_s[t][r] = Xg[(size_t)t * G4 + gg * HIDDEN + q0 + w];
    }

    float cstate = 0.0f;          // live in lane 0 of each wave only

    for (int t = 0; t < TSTEPS; ++t) {
        unsigned long long* hsrc = hbuf + (size_t)(t & 1) * HIDDEN;
        unsigned tag = (unsigned)t;
        float* dst = h_s[t & 1];

        unsigned long long x0 = 0, x1 = 0, x2 = 0, x3 = 0;
        int need = 0xF;
        do {
            if (need & 1) {
                x0 = __hip_atomic_load(hsrc + tid, __ATOMIC_RELAXED,
                                       __HIP_MEMORY_SCOPE_AGENT);
                if ((unsigned)(x0 >> 32) == tag) need &= ~1;
            }
            if (need & 2) {
                x1 = __hip_atomic_load(hsrc + tid + 256, __ATOMIC_RELAXED,
                                       __HIP_MEMORY_SCOPE_AGENT);
                if ((unsigned)(x1 >> 32) == tag) need &= ~2;
            }
            if (need & 4) {
                x2 = __hip_atomic_load(hsrc + tid + 512, __ATOMIC_RELAXED,
                                       __HIP_MEMORY_SCOPE_AGENT);
                if ((unsigned)(x2 >> 32) == tag) need &= ~4;
            }
            if (need & 8) {
                x3 = __hip_atomic_load(hsrc + tid + 768, __ATOMIC_RELAXED,
                                       __HIP_MEMORY_SCOPE_AGENT);
                if ((unsigned)(x3 >> 32) == tag) need &= ~8;
            }
            if (need) __builtin_amdgcn_s_sleep(1);
        } while (need);
        dst[tid]       = __uint_as_float((unsigned)x0);
        dst[tid + 256] = __uint_as_float((unsigned)x1);
        dst[tid + 512] = __uint_as_float((unsigned)x2);
        dst[tid + 768] = __uint_as_float((unsigned)x3);
        __syncthreads();

        float4 a = {0.f, 0.f, 0.f, 0.f};
#pragma unroll
        for (int k = 0; k < 16; ++k) {
            float4 w = wreg[k];
            const float* hv = &dst[(c16 + 16 * k) * 4];
            a.x += w.x * hv[0];
            a.y += w.y * hv[1];
            a.z += w.z * hv[2];
            a.w += w.w * hv[3];
        }
        float sum = (a.x + a.y) + (a.z + a.w);
        sum += __shfl_xor(sum, 1);
        sum += __shfl_xor(sum, 2);
        sum += __shfl_xor(sum, 4);
        sum += __shfl_xor(sum, 8);
        float s0 = __shfl(sum, 0);
        float s1 = __shfl(sum, 16);
        float s2 = __shfl(sum, 32);
        float s3 = __shfl(sum, 48);

        if (lane == 0) {
            float gi = s0 + xg_s[t][wv];
            float gf = s1 + xg_s[t][4 + wv];
            float gg = s2 + xg_s[t][8 + wv];
            float go = s3 + xg_s[t][12 + wv];
            float i_ = 1.f / (1.f + expf(-gi));
            float f_ = 1.f / (1.f + expf(-gf));
            float g_ = tanhf(gg);
            float o_ = 1.f / (1.f + expf(-go));
            cstate = f_ * cstate + i_ * g_;
            float hv = o_ * tanhf(cstate);
            unsigned long long pk =
                ((unsigned long long)(unsigned)(t + 1) << 32) |
                (unsigned long long)__float_as_uint(hv);
            __hip_atomic_store(hbuf + (size_t)((t + 1) & 1) * HIDDEN + hj, pk,
                               __ATOMIC_RELAXED, __HIP_MEMORY_SCOPE_AGENT);
            hs[(size_t)t * HIDDEN + hj] = hv;
        }
        // no trailing barrier: h_s double-buffered, xg_s read-only
    }
}

// ---------------------------------------------------------------------------
// Kernel 4: logits = hs @ fc_W.T + fc_b   [64,1024] x [1024,32000]
// v2: fc_W staged through LDS with wave-contiguous loads (old version had
// each lane walk its own 4KB-strided row -> HBM channel camping, ~0.4 TB/s).
// 500 blocks x (64 t x 64 vocab) tile, 2 blocks/CU, per-thread 4x4 sub-tile.
// NOTE: grid MUST be VOCAB/64 = 500 (R2 crash was VOCAB/32 launch -> OOB).
// ---------------------------------------------------------------------------
__global__ __launch_bounds__(256) void logits_gemm(const float* __restrict__ hs,
                                                   const float* __restrict__ fcW,
                                                   const float* __restrict__ fcb,
                                                   float* __restrict__ out) {
    __shared__ float hs_s[64][RS];
    __shared__ float w_s[64][RS];
    int tid = threadIdx.x;
    int tv  = tid & 15;           // vocab sub-tile
    int tg  = tid >> 4;           // timestep sub-tile
    int j0  = tv * 4;
    int i0  = tg * 4;
    int v0  = blockIdx.x * 64;
    float acc[4][4];
#pragma unroll
    for (int i = 0; i < 4; ++i)
#pragma unroll
        for (int j = 0; j < 4; ++j) acc[i][j] = 0.f;

    for (int c = 0; c < 8; ++c) {
        __syncthreads();
        // stage hs chunk [64][128] — coalesced
        for (int idx = tid; idx < 64 * 32; idx += 256) {
            int r = idx >> 5, f4 = idx & 31;
            float4 h4 = ((const float4*)(hs + (size_t)r * HIDDEN + c * 128))[f4];
            *((float4*)&hs_s[r][f4 * 4]) = h4;
        }
        // stage fc_W chunk [64][128] — consecutive lanes read consecutive 16B
        for (int idx = tid; idx < 64 * 32; idx += 256) {
            int r = idx >> 5, f4 = idx & 31;
            float4 w4 = ((const float4*)(fcW + (size_t)(v0 + r) * HIDDEN + c * 128))[f4];
            *((float4*)&w_s[r][f4 * 4]) = w4;
        }
        __syncthreads();
        for (int f4 = 0; f4 < 32; ++f4) {
            float4 wv[4], hv[4];
#pragma unroll
            for (int j = 0; j < 4; ++j) wv[j] = *((const float4*)&w_s[j0 + j][f4 * 4]);
#pragma unroll
            for (int i = 0; i < 4; ++i) hv[i] = *((const float4*)&hs_s[i0 + i][f4 * 4]);
#pragma unroll
            for (int i = 0; i < 4; ++i)
#pragma unroll
                for (int j = 0; j < 4; ++j) {
                    acc[i][j] += wv[j].x * hv[i].x + wv[j].y * hv[i].y +
                                 wv[j].z * hv[i].z + wv[j].w * hv[i].w;
                }
        }
    }
    float b0 = fcb[v0 + j0 + 0];
    float b1 = fcb[v0 + j0 + 1];
    float b2 = fcb[v0 + j0 + 2];
    float b3 = fcb[v0 + j0 + 3];
#pragma unroll
    for (int i = 0; i < 4; ++i) {
        float4 o = {acc[i][0] + b0, acc[i][1] + b1, acc[i][2] + b2, acc[i][3] + b3};
        *((float4*)&out[(size_t)(i0 + i) * VOCAB + v0 + j0]) = o;
    }
}

// ---------------------------------------------------------------------------
extern "C" void kernel_launch(void* const* d_in, const int* in_sizes, int n_in,
                              void* d_out, int out_size, void* d_ws, size_t ws_size,
                              hipStream_t stream) {
    const int*   caps  = (const int*)  d_in[0];
    const float* feat  = (const float*)d_in[1];
    const float* table = (const float*)d_in[2];
    const float* Wih   = (const float*)d_in[3];
    const float* Whh   = (const float*)d_in[4];
    const float* bih   = (const float*)d_in[5];
    const float* bhh   = (const float*)d_in[6];
    const float* fcW   = (const float*)d_in[7];
    const float* fcb   = (const float*)d_in[8];
    float* out = (float*)d_out;

    char* ws = (char*)d_ws;
    float* xs = (float*)(ws);                                   // 256 KB
    float* Xg = (float*)(ws + 262144);                          // 1 MB
    float* hs = (float*)(ws + 262144 + 1048576);                // 256 KB
    unsigned long long* hbuf =
        (unsigned long long*)(ws + 262144 + 1048576 + 262144);  // 16 KB packed

    // ws is poisoned 0xAA before every timed call: zero the packed h
    // double-buffer (tag==0 <=> valid h==0 initial state).
    hipMemsetAsync(hbuf, 0, 2 * HIDDEN * sizeof(unsigned long long), stream);

    build_xs<<<dim3(TSTEPS, 4), 256, 0, stream>>>(caps, feat, table, xs);
    xg_gemm <<<256, 256, 0, stream>>>(xs, Wih, bih, bhh, Xg);

    void* args[] = {(void*)&Xg, (void*)&Whh, (void*)&hbuf, (void*)&hs};
    hipLaunchCooperativeKernel(lstm_seq, dim3(NBLK), dim3(256), args, 0u, stream);

    logits_gemm<<<VOCAB / 64, 256, 0, stream>>>(hs, fcW, fcb, out);
}